// Round 11
// baseline (55.670 us; speedup 1.0000x reference)
//
#include <hip/hip_runtime.h>

// 1-D hash-grid embedder, 8 levels, 2 feats, fp32, B = 4.19M.
//
// Ledger (all refcheck'd, absmax 4.8e-7): R1 111 -> R3 66.3 (4-thr/point, LDS,
// coalesced wave stores) -> R5 57.3 (persistent + NT) -> R8 56.1 -> R9 54.2
// (x-prefetch before stores) -> R10 51.7 ({t,Delta} b128 image: LDS instr
// 4->2/iter = +2.5us, proving LDS pipe co-critical).
// This round: same lever, last notch. 8 threads/point (s = tid&7 = level) ->
// ONE ds_read_b128 per wave-iter. Stores narrow to float2 (512B/wave bursts,
// still fully contiguous). If neutral, LDS is exonerated and R10's 51.7 is
// the practical ceiling of this structure.
//
// Numerics: res = 16<<l power of two, fx = x*res exact, w = fx - floor(fx)
// bit-identical to reference. Lerp t + w*Delta, dev ~1e-11 vs 2e-6 threshold.

#define NGP_BATCH   4194304
#define NGP_TSIZE   (1 << 19)
#define BLOCK       512
#define PPB         4096                // points per block
#define KITER       (PPB / (BLOCK/8))   // 64 iterations of 64 points
#define NBODY       (KITER / 4)         // 16 bodies of 4 iterations

typedef float f32x2 __attribute__((ext_vector_type(2)));

__global__ __launch_bounds__(BLOCK) void hashenc_kernel(
    const float* __restrict__ x,
    const float* __restrict__ tables,
    float* __restrict__ out)
{
    // level l at off(l) = 16*((1<<l)-1), size 16<<l float4: {t.x, t.y, dx, dy}
    __shared__ float4 sm4[4080];   // 65280 B -> 2 blocks/CU resident

    const int tid = threadIdx.x;

    // ---- stage packed value+delta: sm4[off+e] = {t[e], t[e+1]-t[e]} ----
#pragma unroll
    for (int l = 0; l < 8; ++l) {
        const int n   = 16 << l;                 // e = idx in 0..res-1 (x < 1)
        const int off = 16 * ((1 << l) - 1);
        const float2* __restrict__ src =
            reinterpret_cast<const float2*>(tables) + (size_t)l * NGP_TSIZE;
        for (int e = tid; e < n; e += BLOCK) {
            const float2 a = src[e];
            const float2 b = src[e + 1];
            sm4[off + e] = make_float4(a.x, a.y, b.x - a.x, b.y - a.y);
        }
    }
    __syncthreads();

    const int q = tid >> 3;                      // point-slot within 64
    const int s = tid & 7;                       // level = s
    const float res = (float)(16 << s);
    const int   off = 16 * ((1 << s) - 1);

    const int P0 = blockIdx.x * PPB;
    f32x2* __restrict__ out2 = reinterpret_cast<f32x2*>(out);

    float xc[4], xn[4];
#pragma unroll
    for (int j = 0; j < 4; ++j)
        xc[j] = x[P0 + q + 64 * j];

#pragma unroll
    for (int m = 0; m < NBODY; ++m) {
        // prefetch next body's x BEFORE this body's stores (vmcnt issue order)
        if (m + 1 < NBODY) {
#pragma unroll
            for (int j = 0; j < 4; ++j)
                xn[j] = x[P0 + q + 64 * (4 * (m + 1) + j)];
        }

#pragma unroll
        for (int j = 0; j < 4; ++j) {
            const int   p  = P0 + q + 64 * (4 * m + j);
            const float xv = xc[j];

            const float fx = xv * res;               // exact pow2 scale
            const float fi = floorf(fx);
            const float w  = fx - fi;                // == reference w
            const float4 e = sm4[off + (int)fi];     // ONE ds_read_b128/wave

            f32x2 r;
            r.x = fmaf(w, e.z, e.x);                 // t + w*Delta
            r.y = fmaf(w, e.w, e.y);

            __builtin_nontemporal_store(r, &out2[(size_t)p * 8 + s]); // 512B/wave
        }

        if (m + 1 < NBODY) {
#pragma unroll
            for (int j = 0; j < 4; ++j)
                xc[j] = xn[j];
        }
    }
}

extern "C" void kernel_launch(void* const* d_in, const int* in_sizes, int n_in,
                              void* d_out, int out_size, void* d_ws, size_t ws_size,
                              hipStream_t stream) {
    const float* x      = (const float*)d_in[0];
    const float* tables = (const float*)d_in[1];
    float*       out    = (float*)d_out;

    const int grid = NGP_BATCH / PPB;   // 1024 blocks
    hashenc_kernel<<<grid, BLOCK, 0, stream>>>(x, tables, out);
}

// Round 12
// 51.442 us; speedup vs baseline: 1.0822x; 1.0822x over previous
//
#include <hip/hip_runtime.h>

// 1-D hash-grid embedder, 8 levels, 2 feats, fp32, B = 4.19M.
// FINAL (R10 revert): measured optimum of the structure ladder.
//
// Ledger (all refcheck'd, absmax 4.8e-7): R1 111 -> R3 66.3 (4-thr/point, LDS,
// coalesced 1KB wave stores) -> R5 57.3 (persistent + NT) -> R8 56.1 ->
// R9 54.2 (x-prefetch before stores, vmcnt issue order) -> R10 51.7
// ({t,Delta} b128 image, LDS 4->2 instr/iter) -> R11 55.7 REGRESSION
// (8-thr/point: 512B store bursts + 2x store instrs lose more than the
// last LDS halving gains -> reverted).
// Exonerated: occupancy (2x neutral), dispatch slack (+1us only), b64/b128
// mix at equal bank cycles, LDS 2->1 instr/iter.
// 51.7us = 272MB @ 5.3 TB/s = 84% of measured mixed-stream ceiling.
//
// Numerics: res = 16<<l power of two, fx = x*res exact, w = fx - floor(fx)
// bit-identical to reference. Lerp t + w*Delta, dev ~1e-11 vs 2e-6 threshold.

#define NGP_BATCH   4194304
#define NGP_TSIZE   (1 << 19)
#define BLOCK       512
#define PPB         4096                // points per block
#define KITER       (PPB / (BLOCK/4))   // 32 iterations of 128 points
#define NBODY       (KITER / 4)         // 8 bodies of 4 iterations

typedef float f32x4 __attribute__((ext_vector_type(4)));

__global__ __launch_bounds__(BLOCK) void hashenc_kernel(
    const float* __restrict__ x,
    const float* __restrict__ tables,
    float* __restrict__ out)
{
    // level l at off(l) = 16*((1<<l)-1), size 16<<l float4: {t.x, t.y, dx, dy}
    __shared__ float4 sm4[4080];   // 65280 B -> 2 blocks/CU resident

    const int tid = threadIdx.x;

    // ---- stage packed value+delta: sm4[off+e] = {t[e], t[e+1]-t[e]} ----
#pragma unroll
    for (int l = 0; l < 8; ++l) {
        const int n   = 16 << l;                 // e = idx in 0..res-1 (x < 1)
        const int off = 16 * ((1 << l) - 1);
        const float2* __restrict__ src =
            reinterpret_cast<const float2*>(tables) + (size_t)l * NGP_TSIZE;
        for (int e = tid; e < n; e += BLOCK) {
            const float2 a = src[e];
            const float2 b = src[e + 1];
            sm4[off + e] = make_float4(a.x, a.y, b.x - a.x, b.y - a.y);
        }
    }
    __syncthreads();

    const int q  = tid >> 2;
    const int s  = tid & 3;
    const int l0 = 2 * s;
    const int l1 = 2 * s + 1;
    const float res0 = (float)(16 << l0);
    const float res1 = (float)(16 << l1);
    const int   off0 = 16 * ((1 << l0) - 1);
    const int   off1 = 16 * ((1 << l1) - 1);

    const int P0 = blockIdx.x * PPB;
    f32x4* __restrict__ out4 = reinterpret_cast<f32x4*>(out);

    float xc[4], xn[4];
#pragma unroll
    for (int j = 0; j < 4; ++j)
        xc[j] = x[P0 + q + 128 * j];

#pragma unroll
    for (int m = 0; m < NBODY; ++m) {
        // prefetch next body's x BEFORE this body's stores (vmcnt issue order)
        if (m + 1 < NBODY) {
#pragma unroll
            for (int j = 0; j < 4; ++j)
                xn[j] = x[P0 + q + 128 * (4 * (m + 1) + j)];
        }

#pragma unroll
        for (int j = 0; j < 4; ++j) {
            const int   p  = P0 + q + 128 * (4 * m + j);
            const float xv = xc[j];

            const float fx0 = xv * res0;             // exact pow2 scale
            const float fi0 = floorf(fx0);
            const float w0  = fx0 - fi0;             // == reference w
            const float4 e0 = sm4[off0 + (int)fi0];  // one ds_read_b128

            const float fx1 = xv * res1;
            const float fi1 = floorf(fx1);
            const float w1  = fx1 - fi1;
            const float4 e1 = sm4[off1 + (int)fi1];

            f32x4 r;
            r.x = fmaf(w0, e0.z, e0.x);              // t + w*Delta
            r.y = fmaf(w0, e0.w, e0.y);
            r.z = fmaf(w1, e1.z, e1.x);
            r.w = fmaf(w1, e1.w, e1.y);

            __builtin_nontemporal_store(r, &out4[(size_t)p * 4 + s]);
        }

        if (m + 1 < NBODY) {
#pragma unroll
            for (int j = 0; j < 4; ++j)
                xc[j] = xn[j];
        }
    }
}

extern "C" void kernel_launch(void* const* d_in, const int* in_sizes, int n_in,
                              void* d_out, int out_size, void* d_ws, size_t ws_size,
                              hipStream_t stream) {
    const float* x      = (const float*)d_in[0];
    const float* tables = (const float*)d_in[1];
    float*       out    = (float*)d_out;

    const int grid = NGP_BATCH / PPB;   // 1024 blocks, 2 generations of 512
    hashenc_kernel<<<grid, BLOCK, 0, stream>>>(x, tables, out);
}